// Round 11
// baseline (227.933 us; speedup 1.0000x reference)
//
#include <hip/hip_runtime.h>
#include <hip/hip_bf16.h>

// Cholesky-QR Gram-Schmidt, 16 vectors x dim-256, 32768 rows, fp32,
// layout (16, 32768, 256).
//
// R11: persistent blocks + async global_load_lds double-buffer prefetch.
//  - 1024 blocks (4/CU, LDS-exact) x 1 wave x 32 rows each.
//  - Row data flows HBM -> LDS via __builtin_amdgcn_global_load_lds
//    (16 B/lane, no VGPR round trip); row n+1 streams while row n computes,
//    so the memory pipe never idles during compute phases (the ~35 us gap
//    between R6-best's 199 us and the ~165 us traffic floor).
//  - Top-of-loop s_waitcnt vmcnt(0) is memory-rate-limited, not idle: the
//    next prefetch is always outstanding when a wave waits.
//  - MFMA frags: fp32 from LDS, bf16 hi/lo split at read (3-term Gram).
//  - G redistribution via shfl; fused Cholesky + forward substitution
//    (identical math to the 198.6 us kernel; absmax 1.95e-3).

constexpr int NM   = 16;          // vectors per row
constexpr int NR   = 32768;       // rows
constexpr int D4   = 64;          // float4 per vector
constexpr int FROW = 260;         // floats per vector row in LDS (256 + pad)
constexpr int GRID = 1024;        // 4 blocks/CU on 256 CUs
constexpr int RPB  = NR / GRID;   // 32 rows per block

typedef __attribute__((ext_vector_type(8))) short short8v;  // 8 x bf16
typedef __attribute__((ext_vector_type(4))) float f32x4;

__device__ __forceinline__ float rl(float x, int lane) {
    return __builtin_bit_cast(float,
        __builtin_amdgcn_readlane(__builtin_bit_cast(int, x), lane));
}

// 8 fp32 -> bf16 hi + bf16 lo fragments (hi = bf16(f), lo = bf16(f - hi)).
__device__ __forceinline__ void cvt8(const float4& f0, const float4& f1,
                                     short8v& ah, short8v& al) {
    float f[8] = {f0.x, f0.y, f0.z, f0.w, f1.x, f1.y, f1.z, f1.w};
#pragma unroll
    for (int j = 0; j < 8; ++j) {
        unsigned short hb =
            __builtin_bit_cast(unsigned short, __float2bfloat16(f[j]));
        ah[j] = (short)hb;
        float hv = __builtin_bit_cast(float, (unsigned int)hb << 16);  // exact
        al[j] = (short)__builtin_bit_cast(unsigned short,
                                          __float2bfloat16(f[j] - hv));
    }
}

__global__ __launch_bounds__(64) void gs_kernel(const float* __restrict__ x,
                                                float* __restrict__ out) {
    __shared__ __align__(16) float sm[2][NM * FROW];   // 2 x 16.64 KB

    const int lane = threadIdx.x;
    const int bid  = blockIdx.x;
    const int vec  = lane & 15;   // vector owned in the MFMA fragment
    const int kgrp = lane >> 4;   // k-group 0..3

    const float4* __restrict__ xi = reinterpret_cast<const float4*>(x);
    float4* __restrict__ oo       = reinterpret_cast<float4*>(out);

    // Async-stage one row's 16 KB into LDS buffer b: per vector i, 64 lanes
    // x 16 B. LDS dest is wave-uniform base + lane*16 (linear, no swizzle);
    // global source is per-lane.
    auto prefetch = [&](int b, int row) {
#pragma unroll
        for (int i = 0; i < NM; ++i) {
            const float4* src = xi + (size_t)(i * NR + row) * D4 + lane;
            __builtin_amdgcn_global_load_lds(
                (const __attribute__((address_space(1))) void*)src,
                (__attribute__((address_space(3))) void*)&sm[b][i * FROW],
                16, 0, 0);
        }
    };

    int buf = 0;
    prefetch(0, bid);

    for (int it = 0; it < RPB; ++it) {
        const int row = it * GRID + bid;

        // Wait for this buffer's prefetch (and old stores). Memory pipe stays
        // busy during the wait: the loads being waited on ARE the traffic.
        asm volatile("s_waitcnt vmcnt(0)" ::: "memory");
        __builtin_amdgcn_sched_barrier(0);

        // Stream next row into the other buffer while this row computes.
        if (it + 1 < RPB) prefetch(buf ^ 1, row + GRID);

        // G = V V^T via MFMA (bf16 hi/lo split, 3 terms), frags from LDS.
        f32x4 g = {0.0f, 0.0f, 0.0f, 0.0f};
#pragma unroll
        for (int c = 0; c < 8; ++c) {
            const int off = vec * FROW + c * 32 + kgrp * 8;
            float4 f0 = *reinterpret_cast<const float4*>(&sm[buf][off]);
            float4 f1 = *reinterpret_cast<const float4*>(&sm[buf][off + 4]);
            short8v ah, al;
            cvt8(f0, f1, ah, al);
            g = __builtin_amdgcn_mfma_f32_16x16x32_bf16(ah, ah, g, 0, 0, 0);
            g = __builtin_amdgcn_mfma_f32_16x16x32_bf16(ah, al, g, 0, 0, 0);
            g = __builtin_amdgcn_mfma_f32_16x16x32_bf16(al, ah, g, 0, 0, 0);
        }

        // Lane-private fp32 copies for the solve (lane l: elems 4l..4l+3).
        float4 v[NM];
#pragma unroll
        for (int i = 0; i < NM; ++i)
            v[i] = *reinterpret_cast<const float4*>(&sm[buf][i * FROW + 4 * lane]);

        // a[n] = G[vec][n] via shfl (C/D map orientation-proof by symmetry).
        float a[NM];
#pragma unroll
        for (int n = 0; n < NM; ++n)
            a[n] = __shfl(g[n & 3], vec + 16 * (n >> 2), 64);

        // Fused right-looking Cholesky + forward substitution; stores spread
        // across the solve.
#pragma unroll
        for (int j = 0; j < NM; ++j) {
            float p   = rl(a[j], j);                    // pivot = ||w_j||^2
            float inv = (p > 0.0f) ? rsqrtf(p) : 0.0f;  // safe-div
            v[j].x *= inv; v[j].y *= inv; v[j].z *= inv; v[j].w *= inv;
            oo[(size_t)(j * NR + row) * D4 + lane] = v[j];
            a[j] *= inv;                                // column j of L
#pragma unroll
            for (int t = j + 1; t < NM; ++t) {
                float u = rl(a[j], t);                  // L[t][j] = <v_t, q_j>
                a[t]  = fmaf(-u, a[j], a[t]);
                v[t].x = fmaf(-u, v[j].x, v[t].x);
                v[t].y = fmaf(-u, v[j].y, v[t].y);
                v[t].z = fmaf(-u, v[j].z, v[t].z);
                v[t].w = fmaf(-u, v[j].w, v[t].w);
            }
        }

        buf ^= 1;
    }
}

extern "C" void kernel_launch(void* const* d_in, const int* in_sizes, int n_in,
                              void* d_out, int out_size, void* d_ws, size_t ws_size,
                              hipStream_t stream) {
    const float* x = (const float*)d_in[0];
    float* out     = (float*)d_out;
    dim3 grid(GRID);   // persistent: 4 blocks/CU, 32 rows each
    dim3 block(64);
    hipLaunchKernelGGL(gs_kernel, grid, block, 0, stream, x, out);
}

// Round 13
// 202.065 us; speedup vs baseline: 1.1280x; 1.1280x over previous
//
#include <hip/hip_runtime.h>
#include <hip/hip_bf16.h>

// Cholesky-QR Gram-Schmidt, 16 vectors x dim-256, 32768 rows, fp32,
// layout (16, 32768, 256). Best-known structure (R5, 198.6 us) minus its
// removable overheads, plus nontemporal stores.
//
// R13 = R12 with the compile fix: __builtin_nontemporal_store requires a
// native clang vector type, so Q writes go through f32x4 (ext_vector_type)
// instead of HIP's float4 wrapper.
//  - single fp32 LDS staging buffer (16.6 KB), bf16 hi/lo split at frag
//    read (cvt8) -> half the ds_writes, one barrier total.
//  - G redistribution via 16 __shfl (drops sm_G buffer + 2nd barrier).
//  - nontemporal Q stores: output doesn't allocate in L3 -> input keeps
//    more of the 256 MB L3 across replays -> FETCH_SIZE should drop.

constexpr int NM   = 16;     // vectors per row
constexpr int NR   = 32768;  // rows
constexpr int D4   = 64;     // float4 per vector
constexpr int FROW = 260;    // floats per vector row in LDS (256 + 4 pad)

typedef __attribute__((ext_vector_type(8))) short short8v;  // 8 x bf16
typedef __attribute__((ext_vector_type(4))) float f32x4;

__device__ __forceinline__ float rl(float x, int lane) {
    return __builtin_bit_cast(float,
        __builtin_amdgcn_readlane(__builtin_bit_cast(int, x), lane));
}

// 8 fp32 -> bf16 hi + bf16 lo fragments (hi = bf16(f), lo = bf16(f - hi)).
__device__ __forceinline__ void cvt8(const float4& f0, const float4& f1,
                                     short8v& ah, short8v& al) {
    float f[8] = {f0.x, f0.y, f0.z, f0.w, f1.x, f1.y, f1.z, f1.w};
#pragma unroll
    for (int j = 0; j < 8; ++j) {
        unsigned short hb =
            __builtin_bit_cast(unsigned short, __float2bfloat16(f[j]));
        ah[j] = (short)hb;
        float hv = __builtin_bit_cast(float, (unsigned int)hb << 16);  // exact
        al[j] = (short)__builtin_bit_cast(unsigned short,
                                          __float2bfloat16(f[j] - hv));
    }
}

__global__ __launch_bounds__(64) void gs_kernel(const float* __restrict__ x,
                                                float* __restrict__ out) {
    __shared__ __align__(16) float sm[NM * FROW];   // 16640 B

    const int lane = threadIdx.x;
    const int row  = blockIdx.x;
    const int vec  = lane & 15;   // vector owned in the MFMA fragment
    const int kgrp = lane >> 4;   // k-group 0..3

    const float4* __restrict__ xi = reinterpret_cast<const float4*>(x);
    f32x4* __restrict__ oo        = reinterpret_cast<f32x4*>(out);

    // Coalesced load: lane l owns elements [4l, 4l+4) of every vector.
    float4 v[NM];
#pragma unroll
    for (int i = 0; i < NM; ++i)
        v[i] = xi[(size_t)(i * NR + row) * D4 + lane];

    // Stage fp32 to LDS (16 x ds_write_b128).
#pragma unroll
    for (int i = 0; i < NM; ++i)
        *reinterpret_cast<float4*>(&sm[i * FROW + 4 * lane]) = v[i];
    __syncthreads();

    // G = V V^T via MFMA (bf16 hi/lo split at read, 3 terms).
    f32x4 g = {0.0f, 0.0f, 0.0f, 0.0f};
#pragma unroll
    for (int c = 0; c < 8; ++c) {
        const int off = vec * FROW + c * 32 + kgrp * 8;
        float4 f0 = *reinterpret_cast<const float4*>(&sm[off]);
        float4 f1 = *reinterpret_cast<const float4*>(&sm[off + 4]);
        short8v ah, al;
        cvt8(f0, f1, ah, al);
        g = __builtin_amdgcn_mfma_f32_16x16x32_bf16(ah, ah, g, 0, 0, 0);
        g = __builtin_amdgcn_mfma_f32_16x16x32_bf16(ah, al, g, 0, 0, 0);
        g = __builtin_amdgcn_mfma_f32_16x16x32_bf16(al, ah, g, 0, 0, 0);
    }

    // a[n] = G[vec][n] via shfl (C/D map orientation-proof by G's symmetry).
    float a[NM];
#pragma unroll
    for (int n = 0; n < NM; ++n)
        a[n] = __shfl(g[n & 3], vec + 16 * (n >> 2), 64);

    // Fused right-looking Cholesky + forward substitution; nontemporal
    // stores keep the output out of L3.
#pragma unroll
    for (int j = 0; j < NM; ++j) {
        float p   = rl(a[j], j);                    // pivot = ||w_j||^2
        float inv = (p > 0.0f) ? rsqrtf(p) : 0.0f;  // safe-div
        v[j].x *= inv; v[j].y *= inv; v[j].z *= inv; v[j].w *= inv;   // q_j
        f32x4 q = {v[j].x, v[j].y, v[j].z, v[j].w};
        __builtin_nontemporal_store(q, &oo[(size_t)(j * NR + row) * D4 + lane]);
        a[j] *= inv;                                // column j of L
#pragma unroll
        for (int t = j + 1; t < NM; ++t) {
            float u = rl(a[j], t);                  // L[t][j] = <v_t, q_j>
            a[t]  = fmaf(-u, a[j], a[t]);           // Cholesky trailing update
            v[t].x = fmaf(-u, v[j].x, v[t].x);      // v_t -= L[t][j] * q_j
            v[t].y = fmaf(-u, v[j].y, v[t].y);
            v[t].z = fmaf(-u, v[j].z, v[t].z);
            v[t].w = fmaf(-u, v[j].w, v[t].w);
        }
    }
}

extern "C" void kernel_launch(void* const* d_in, const int* in_sizes, int n_in,
                              void* d_out, int out_size, void* d_ws, size_t ws_size,
                              hipStream_t stream) {
    const float* x = (const float*)d_in[0];
    float* out     = (float*)d_out;
    dim3 grid(NR);     // one wave per row
    dim3 block(64);
    hipLaunchKernelGGL(gs_kernel, grid, block, 0, stream, x, out);
}